// Round 1
// 1277.973 us; speedup vs baseline: 1.1487x; 1.1487x over previous
//
#include <hip/hip_runtime.h>

// Seq2Seq: enc-LSTM -> dec-LSTM -> vocab projection.  B=32 S=T=128 E=128 H=256 V=32000.
//
// Structure:
//  prep_kernel : pack Whh_{enc,dec} to f16x2 [phase][k-dword][gate] (coalesced reg reload),
//                convert W_out to bf16.
//  xg_kernel   : xg[p,b,t,g] = emb[token] . Wih[g,:]  (fp32 tiled GEMM w/ gather)
//  lstm_kernel : ONE 1024-thread WG per batch (32 WGs). Thread t owns gate row g=t.
//                Weight row (128 f16x2 dwords) split: 92 dwords in VGPRs + 36 dwords in a
//                thread-private LDS slice (147 KB) so the 16-wave WG fits the 128-VGPR cap.
//                h state (256 f16 = 128 dwords) lives in LDS; the whole recurrence step is
//                dot -> gact write -> barrier -> c/h update -> h2 write -> barrier.
//                NO cross-WG exchange, no global atomics, no spin-waits (the previous
//                2-WG-per-batch design spent ~95% of its time in agent-scope flag/xbuf
//                round-trips). xg is prefetched one step ahead to hide HBM latency.
//  proj_kernel : bf16 MFMA 16x16x32, 128x128 tile, BK=128, global_load_lds(16B) staging with
//                XOR-swizzle (k8' = k8 ^ (m&15)) so frag ds_read_b128 is 2-way (free) and the
//                wave-uniform-base+lane*16 constraint of global_load_lds is respected.
//
// Workspace layout (57,344,000 B; xbuf/xflag slots now unused but kept for layout stability):
//   xg     f32 [2*32*128][1024]                     33,554,432
//   WhhP   u32 [2][128][1024]   (f16x2 pairs)        1,048,576
//   WoutB  bf16[32000][256]                         16,384,000
//   decO   bf16[4096][256]                           2,097,152
//   (unused)                                         4,259,840

typedef _Float16 half2v __attribute__((ext_vector_type(2)));
typedef short bf16x8 __attribute__((ext_vector_type(8)));
typedef float f32x4 __attribute__((ext_vector_type(4)));

__device__ __forceinline__ unsigned short f2h_bits(float f) {
  _Float16 h = (_Float16)f;
  return __builtin_bit_cast(unsigned short, h);
}

__device__ __forceinline__ unsigned short f2bf_bits(float f) {
  unsigned u = __builtin_bit_cast(unsigned, f);
  u += 0x7fffu + ((u >> 16) & 1u);
  return (unsigned short)(u >> 16);
}

__device__ __forceinline__ float fdot2u(unsigned wu, unsigned hu, float acc) {
#if defined(__has_builtin) && __has_builtin(__builtin_amdgcn_fdot2)
  return __builtin_amdgcn_fdot2(__builtin_bit_cast(half2v, wu),
                                __builtin_bit_cast(half2v, hu), acc, false);
#else
  half2v a = __builtin_bit_cast(half2v, wu);
  half2v b = __builtin_bit_cast(half2v, hu);
  return acc + (float)a[0] * (float)b[0] + (float)a[1] * (float)b[1];
#endif
}

__device__ __forceinline__ float tanh_fast(float x) {
  float e = __expf(2.f * x);
  return 1.f - 2.f / (e + 1.f);
}

__device__ __forceinline__ float sigmoid_fast(float x) {
  return 1.f / (1.f + __expf(-x));
}

__device__ __forceinline__ void gload_lds16(const void* g, void* l) {
#if defined(__has_builtin) && __has_builtin(__builtin_amdgcn_global_load_lds)
  __builtin_amdgcn_global_load_lds(
      (const __attribute__((address_space(1))) void*)g,
      (__attribute__((address_space(3))) void*)l, 16, 0, 0);
#else
  *(uint4*)l = *(const uint4*)g;
#endif
}

// ---------------------------------------------------------------- prep ----
__global__ void prep_kernel(const float* __restrict__ WhhE, const float* __restrict__ WhhD,
                            const float* __restrict__ Wout,
                            unsigned* __restrict__ WhhP, unsigned short* __restrict__ WoutB) {
  int i = blockIdx.x * blockDim.x + threadIdx.x;
  int stride = gridDim.x * blockDim.x;
  // Whh pack: layout [p][d][g], d = k-pair dword 0..127, g = gate row 0..1023
  for (int idx = i; idx < 262144; idx += stride) {
    int p = idx >> 17;
    int rem = idx & 131071;
    int d = rem >> 10;
    int g = rem & 1023;
    const float* W = p ? WhhD : WhhE;
    float a = W[g * 256 + 2 * d];
    float b = W[g * 256 + 2 * d + 1];
    WhhP[idx] = (unsigned)f2h_bits(a) | ((unsigned)f2h_bits(b) << 16);
  }
  for (int idx = i; idx < 8192000; idx += stride) {
    WoutB[idx] = f2bf_bits(Wout[idx]);
  }
}

// ------------------------------------------------------------------ xg ----
// xg[m][n] = sum_e emb[tok(m)][e] * Wih[n][e],  m = p*4096 + b*128 + t (8192 rows), n = 0..1023
__global__ __launch_bounds__(256, 2) void xg_kernel(
    const int* __restrict__ x, const int* __restrict__ y,
    const float* __restrict__ enc_emb, const float* __restrict__ dec_emb,
    const float* __restrict__ Wih_enc, const float* __restrict__ Wih_dec,
    float* __restrict__ xg) {
  __shared__ float Al[64][132];
  __shared__ float Bl[64][132];
  __shared__ int tok[64];
  const int nb = blockIdx.x;     // 0..15  (n tile)
  const int mbb = blockIdx.y;    // 0..127 (m tile)
  const int m0 = mbb * 64;
  const int p = mbb >> 6;
  const int tid = threadIdx.x;

  if (tid < 64) {
    int mloc = (m0 + tid) & 4095;  // index into x/y flat [32*128]
    tok[tid] = p ? y[mloc] : x[mloc];
  }
  __syncthreads();

  const float* emb = p ? dec_emb : enc_emb;
  const float* Wih = p ? Wih_dec : Wih_enc;
  {
    int ri = tid & 63, seg = tid >> 6;  // 64 rows x 4 segments of 32 floats
    const float* er = emb + (size_t)tok[ri] * 128 + seg * 32;
    const float* wr = Wih + (size_t)(nb * 64 + ri) * 128 + seg * 32;
#pragma unroll
    for (int c = 0; c < 8; ++c) {
      *(float4*)&Al[ri][seg * 32 + c * 4] = *(const float4*)&er[c * 4];
      *(float4*)&Bl[ri][seg * 32 + c * 4] = *(const float4*)&wr[c * 4];
    }
  }
  __syncthreads();

  const int tx = tid & 15, ty = tid >> 4;
  float acc[4][4];
#pragma unroll
  for (int mm = 0; mm < 4; ++mm)
#pragma unroll
    for (int nn = 0; nn < 4; ++nn) acc[mm][nn] = 0.f;

  for (int k4 = 0; k4 < 32; ++k4) {
    float4 av[4], bv[4];
#pragma unroll
    for (int mm = 0; mm < 4; ++mm) av[mm] = *(const float4*)&Al[mm * 16 + ty][k4 * 4];
#pragma unroll
    for (int nn = 0; nn < 4; ++nn) bv[nn] = *(const float4*)&Bl[nn * 16 + tx][k4 * 4];
#pragma unroll
    for (int mm = 0; mm < 4; ++mm)
#pragma unroll
      for (int nn = 0; nn < 4; ++nn) {
        acc[mm][nn] = fmaf(av[mm].x, bv[nn].x, acc[mm][nn]);
        acc[mm][nn] = fmaf(av[mm].y, bv[nn].y, acc[mm][nn]);
        acc[mm][nn] = fmaf(av[mm].z, bv[nn].z, acc[mm][nn]);
        acc[mm][nn] = fmaf(av[mm].w, bv[nn].w, acc[mm][nn]);
      }
  }
#pragma unroll
  for (int mm = 0; mm < 4; ++mm)
#pragma unroll
    for (int nn = 0; nn < 4; ++nn)
      xg[(size_t)(m0 + mm * 16 + ty) * 1024 + nb * 64 + nn * 16 + tx] = acc[mm][nn];
}

// ---------------------------------------------------------------- lstm ----
// One WG per batch. 1024 threads; thread t owns gate row g=t (q=t>>8 in {i,f,g,o},
// unit j=t&255). Weight row: wqd[0..91] in VGPRs (k-pairs 0..91), WL LDS slice holds
// k-pairs 92..127 (36 dwords/thread, thread-private column => no staging barrier).
// h2[128] dwords = full h as f16 pairs, LDS. gact[4][256] = gate activations.
__global__ __launch_bounds__(1024, 1) void lstm_kernel(
    const float* __restrict__ xg, const unsigned* __restrict__ WhhP,
    const float* __restrict__ bih_enc, const float* __restrict__ bhh_enc,
    const float* __restrict__ bih_dec, const float* __restrict__ bhh_dec,
    unsigned short* __restrict__ decO) {   // bf16 [4096][256]
  const int b = blockIdx.x;   // batch 0..31
  const int t = threadIdx.x;  // 0..1023
  const int g = t;            // gate row
  const int q = t >> 8;       // gate class 0..3 (i,f,g,o) -- wave-uniform
  const int j = t & 255;      // unit

  __shared__ __align__(16) unsigned h2[128];   // full h as f16x2 pairs (256 f16)
  __shared__ float gact[4][256];
  __shared__ unsigned WL[18 * 2048];           // [dp][g][2] : k-pairs 92..127, 147,456 B

  if (t < 128) h2[t] = 0u;
  float c_r = 0.f;  // cell state, owned by t<256 threads (unit j=t)
  __syncthreads();

  unsigned wqd[92];  // register-resident f16x2 weight row, k-pairs 0..91
  float bias_g = 0.f;

  // prefetch xg for s=0
  float xgv_n = xg[(size_t)(b << 7) * 1024 + g];

  for (int s = 0; s < 256; ++s) {
    const int p = s >> 7;
    const int tt = s & 127;

    if ((s & 127) == 0) {  // phase start: (re)load weights + bias
      const unsigned* base = WhhP + (p << 17);
#pragma unroll
      for (int d = 0; d < 92; ++d) wqd[d] = base[(d << 10) + g];
      // LDS slice: thread-private column, b64-pair layout [dp][g][2]
#pragma unroll
      for (int dd = 0; dd < 36; ++dd)
        WL[((dd >> 1) << 11) + (g << 1) + (dd & 1)] = base[((92 + dd) << 10) + g];
      bias_g = p ? (bih_dec[g] + bhh_dec[g]) : (bih_enc[g] + bhh_enc[g]);
    }

    const float xgv = xgv_n;
    if (s < 255) {  // prefetch next step's xg (independent of recurrence)
      const int sn = s + 1;
      xgv_n = xg[(size_t)(((sn >> 7) << 12) + (b << 7) + (sn & 127)) * 1024 + g];
    }

    // full-k dot: h2 reads are wave-uniform (broadcast, conflict-free)
    float a0 = 0.f, a1 = 0.f, a2 = 0.f, a3 = 0.f;
#pragma unroll
    for (int c = 0; c < 23; ++c) {
      const uint4 hv = *(const uint4*)&h2[c << 2];
      a0 = fdot2u(wqd[4 * c + 0], hv.x, a0);
      a1 = fdot2u(wqd[4 * c + 1], hv.y, a1);
      a2 = fdot2u(wqd[4 * c + 2], hv.z, a2);
      a3 = fdot2u(wqd[4 * c + 3], hv.w, a3);
    }
#pragma unroll
    for (int c = 23; c < 32; ++c) {
      const uint4 hv = *(const uint4*)&h2[c << 2];
      const int dp0 = (4 * c - 92) >> 1;  // 0,2,4,...,16
      const uint2 w01 = *(const uint2*)&WL[(dp0 << 11) + (g << 1)];
      const uint2 w23 = *(const uint2*)&WL[((dp0 + 1) << 11) + (g << 1)];
      a0 = fdot2u(w01.x, hv.x, a0);
      a1 = fdot2u(w01.y, hv.y, a1);
      a2 = fdot2u(w23.x, hv.z, a2);
      a3 = fdot2u(w23.y, hv.w, a3);
    }
    const float accf = bias_g + xgv + ((a0 + a1) + (a2 + a3));

    // activation (q wave-uniform: no divergence)
    const float act = (q == 2) ? tanh_fast(accf) : sigmoid_fast(accf);
    gact[q][j] = act;
    __syncthreads();

    if (t < 256) {  // unit j=t update (waves 0..3 fully active -> shfl safe)
      const float iv = gact[0][t];
      const float fv = gact[1][t];
      const float gv = gact[2][t];
      const float ov = gact[3][t];
      c_r = fv * c_r + iv * gv;
      const float hh = ov * tanh_fast(c_r);
      if (p) decO[(size_t)((b << 7) + tt) * 256 + t] = f2bf_bits(hh);
      const float hn = __shfl_down(hh, 1, 64);
      if (!(t & 1))
        h2[t >> 1] = (unsigned)f2h_bits(hh) | ((unsigned)f2h_bits(hn) << 16);
    }
    __syncthreads();  // h2 update visible before next step's dot
  }
}

// ---------------------------------------------------------------- proj ----
// out[m][n] = sum_k A[m][k]*Bw[n][k] + bias[n];  M=4096 N=32000 K=256, bf16 MFMA
__global__ __launch_bounds__(256, 2) void proj_kernel(
    const unsigned short* __restrict__ A,   // decO bf16 [4096][256]
    const unsigned short* __restrict__ Bw,  // WoutB bf16 [32000][256]
    const float* __restrict__ bias, float* __restrict__ out) {
  __shared__ unsigned short Al[128 * 128];
  __shared__ unsigned short Bl[128 * 128];
  const int mb = blockIdx.x;  // 0..31
  const int nb = blockIdx.y;  // 0..249
  const int tid = threadIdx.x;
  const int wv = tid >> 6, ln = tid & 63;
  const int wm = wv & 1, wn = wv >> 1;  // 2x2 waves, each 64x64
  const int l16 = ln & 15, lq = ln >> 4;

  f32x4 acc[4][4] = {};

  for (int kc = 0; kc < 2; ++kc) {
    // stage A then B: slot st -> (m = st>>4, k8 = st&15); source k8 swizzled by m&15
#pragma unroll
    for (int it = 0; it < 8; ++it) {
      int st = it * 256 + tid;
      int m = st >> 4, k8 = st & 15;
      const unsigned short* gp =
          A + (size_t)(mb * 128 + m) * 256 + kc * 128 + ((k8 ^ (m & 15)) << 3);
      gload_lds16(gp, &Al[st << 3]);
    }
#pragma unroll
    for (int it = 0; it < 8; ++it) {
      int st = it * 256 + tid;
      int m = st >> 4, k8 = st & 15;
      const unsigned short* gp =
          Bw + (size_t)(nb * 128 + m) * 256 + kc * 128 + ((k8 ^ (m & 15)) << 3);
      gload_lds16(gp, &Bl[st << 3]);
    }
    asm volatile("s_waitcnt vmcnt(0)" ::: "memory");
    __syncthreads();

#pragma unroll
    for (int ks = 0; ks < 4; ++ks) {
      const int k8 = (ks << 2) + lq;
      bf16x8 af[4], bf[4];
#pragma unroll
      for (int mt = 0; mt < 4; ++mt) {
        int m = (wm << 6) + (mt << 4) + l16;
        af[mt] = *(const bf16x8*)&Al[(m << 7) + ((k8 ^ (m & 15)) << 3)];
      }
#pragma unroll
      for (int nt = 0; nt < 4; ++nt) {
        int n = (wn << 6) + (nt << 4) + l16;
        bf[nt] = *(const bf16x8*)&Bl[(n << 7) + ((k8 ^ (n & 15)) << 3)];
      }
#pragma unroll
      for (int mt = 0; mt < 4; ++mt)
#pragma unroll
        for (int nt = 0; nt < 4; ++nt)
          acc[mt][nt] = __builtin_amdgcn_mfma_f32_16x16x32_bf16(af[mt], bf[nt],
                                                                acc[mt][nt], 0, 0, 0);
    }
    __syncthreads();
  }

  // epilogue: D row = (lq*4 + rr) within 16 (M), col = l16 (N)
#pragma unroll
  for (int nt = 0; nt < 4; ++nt) {
    const int gcol = nb * 128 + (wn << 6) + (nt << 4) + l16;
    const float bs = bias[gcol];
#pragma unroll
    for (int mt = 0; mt < 4; ++mt) {
      const int grow0 = mb * 128 + (wm << 6) + (mt << 4) + (lq << 2);
#pragma unroll
      for (int rr = 0; rr < 4; ++rr)
        out[(size_t)(grow0 + rr) * 32000 + gcol] = acc[mt][nt][rr] + bs;
    }
  }
}

// -------------------------------------------------------------- launch ----
extern "C" void kernel_launch(void* const* d_in, const int* in_sizes, int n_in,
                              void* d_out, int out_size, void* d_ws, size_t ws_size,
                              hipStream_t stream) {
  const int* x = (const int*)d_in[0];
  const int* y = (const int*)d_in[1];
  const float* enc_emb = (const float*)d_in[2];
  const float* dec_emb = (const float*)d_in[3];
  const float* Wih_enc = (const float*)d_in[4];
  const float* Whh_enc = (const float*)d_in[5];
  const float* bih_enc = (const float*)d_in[6];
  const float* bhh_enc = (const float*)d_in[7];
  const float* Wih_dec = (const float*)d_in[8];
  const float* Whh_dec = (const float*)d_in[9];
  const float* bih_dec = (const float*)d_in[10];
  const float* bhh_dec = (const float*)d_in[11];
  const float* W_out = (const float*)d_in[12];
  const float* b_out = (const float*)d_in[13];

  char* ws = (char*)d_ws;
  float* xg = (float*)ws;                                       // 33,554,432
  unsigned* WhhP = (unsigned*)(ws + 33554432);                  //  1,048,576
  unsigned short* WoutB = (unsigned short*)(ws + 34603008);     // 16,384,000
  unsigned short* decO = (unsigned short*)(ws + 50987008);      //  2,097,152
  if (ws_size < 57344000) return;  // insufficient workspace (would corrupt)

  prep_kernel<<<4096, 256, 0, stream>>>(Whh_enc, Whh_dec, W_out, WhhP, WoutB);
  xg_kernel<<<dim3(16, 128), 256, 0, stream>>>(x, y, enc_emb, dec_emb, Wih_enc, Wih_dec, xg);
  lstm_kernel<<<32, 1024, 0, stream>>>(xg, WhhP, bih_enc, bhh_enc, bih_dec, bhh_dec, decO);
  proj_kernel<<<dim3(32, 250), 256, 0, stream>>>(decO, WoutB, b_out, (float*)d_out);
}